// Round 2
// baseline (63.965 us; speedup 1.0000x reference)
//
#include <hip/hip_runtime.h>
#include <hip/hip_bf16.h>

// ws layout (requires ws_size >= 17039360 B):
//   [0, 221184)        : weights as bf16 in MFMA B-fragment order
//   [221184, 221440)   : 256 B of zeros (OOB halo source)
//   [262144, 17039360) : x_t = x transposed to [b][s][c] bf16 (16 MiB)
#define WS_W_OFF    0
#define WS_ZERO_OFF 221184
#define WS_XT_OFF   262144

typedef __attribute__((ext_vector_type(8))) short s16x8;
typedef __attribute__((ext_vector_type(4))) float f32x4;

#define GLOBAL_AS __attribute__((address_space(1)))
#define LDS_AS    __attribute__((address_space(3)))

__device__ __forceinline__ unsigned short f2bf(float f) {
  // round-to-nearest-even bf16 (inputs are normal randoms; no NaN handling needed)
  unsigned u = __builtin_bit_cast(unsigned, f);
  u = u + 0x7fffu + ((u >> 16) & 1u);
  return (unsigned short)(u >> 16);
}

// ---------------------------------------------------------------------------
// Fused prep: blocks [0,432) repack weights; blocks [432,4528) transpose x.
//
// Weights: W[cout][cin][tap] fp32 -> bf16 fragments.
// Fragment f = tap*8 + st2*4 + nf holds B[n][k] for n = nf*16 + (lane&15),
// cin = st2*32 + (lane>>4)*8 + j  (16x16x32 MFMA B layout, contiguous-k per lane).
// bf16 index = (f*64 + lane)*8 + j.
//
// x: NCDHW fp32 -> x_t[b][s][c] bf16 (channels-last). Reads coalesced along s.
__global__ void prep_kernel(const float* __restrict__ x,
                            const float* __restrict__ w,
                            unsigned short* __restrict__ wsw,
                            float* __restrict__ zeros,
                            unsigned short* __restrict__ xt) {
  int blk = blockIdx.x;
  if (blk < 432) {
    int t = blk * 256 + threadIdx.x;             // 110592 threads exactly
    int tap  = t % 27;
    int cin  = (t / 27) & 63;
    int cout = t / (27 * 64);
    int st2 = cin >> 5;
    int q   = (cin >> 3) & 3;
    int j   = cin & 7;
    int nf  = cout >> 4;
    int lane = q * 16 + (cout & 15);
    int dst = (((tap * 2 + st2) * 4 + nf) * 64 + lane) * 8 + j;
    wsw[dst] = f2bf(w[t]);
    if (t < 64) zeros[t] = 0.0f;
  } else {
    int t  = (blk - 432) * 256 + threadIdx.x;    // 1048576 threads
    int s  = t & 32767;
    int c8 = (t >> 15) & 7;
    int b  = t >> 18;
    const float* src = x + (size_t)(b * 64 + c8 * 8) * 32768 + s;
    s16x8 v;
    #pragma unroll
    for (int k = 0; k < 8; ++k) v[k] = (short)f2bf(src[(size_t)k * 32768]);
    *(s16x8*)(xt + (size_t)(b * 32768 + s) * 64 + c8 * 8) = v;
  }
}

// ---------------------------------------------------------------------------
// Implicit-GEMM conv. Block = (b, z-pair, y-pair): 128 output positions x 64 couts.
// 2 waves; wave w owns z-row z0+w: M_w = 64 positions (2 y-rows x 32 x) x 64 couts.
// K-loop: 27 taps x (K=64 as 2 MFMA K-steps). A from LDS halo (XOR-swizzled),
// B from ws in registers (double-buffered, L1-resident) -- zero barriers in loop.
__global__ __launch_bounds__(128, 1) void conv_kernel(const float* __restrict__ bias,
                                                      float* __restrict__ out,
                                                      const char* __restrict__ ws) {
  __shared__ unsigned char halo[4 * 4 * 34 * 128];   // 69632 B -> 2 blocks/CU

  const int tid  = threadIdx.x;
  const int lane = tid & 63;
  const int w    = tid >> 6;                     // wave id: 0 or 1
  const int bid  = blockIdx.x;
  const int yt = bid & 15, zt = (bid >> 4) & 15, b = bid >> 8;
  const int z0 = zt * 2, y0 = yt * 2;

  // ---- stage halo: 544 positions x 128 B via global_load_lds (16 B/lane) ----
  {
    const int slot = lane & 7;
    const int psub = lane >> 3;
    for (int i = 0; i < 34; ++i) {
      int cb  = (i * 2 + w) * 8;                 // 8 positions per wave-iter
      int pos = cb + psub;
      int hz = pos / 136; int rem = pos - hz * 136;
      int hy = rem / 34;  int hx = rem - hy * 34;
      int gz = z0 + hz - 1, gy = y0 + hy - 1, gx = hx - 1;
      bool inb = ((unsigned)gz < 32u) & ((unsigned)gy < 32u) & ((unsigned)gx < 32u);
      int s = (gz * 32 + gy) * 32 + gx;
      // source-side swizzle so that LDS slot 'slot' holds cin-chunk (slot ^ (hx&7))
      int src = inb ? (WS_XT_OFF + (b * 32768 + s) * 128 + ((slot ^ (hx & 7)) << 4))
                    : WS_ZERO_OFF;
      __builtin_amdgcn_global_load_lds(
          (const GLOBAL_AS void*)(ws + src),
          (LDS_AS void*)(&halo[cb * 128 + (lane << 4)]),
          16, 0, 0);
    }
  }

  const s16x8* __restrict__ wfr = (const s16x8*)(ws + WS_W_OFF);

  f32x4 zero4 = {0.f, 0.f, 0.f, 0.f};
  f32x4 acc[4][4];
  #pragma unroll
  for (int mf = 0; mf < 4; ++mf)
    #pragma unroll
    for (int nf = 0; nf < 4; ++nf) acc[mf][nf] = zero4;

  s16x8 BA[8], BB[8];
  #pragma unroll
  for (int f = 0; f < 8; ++f) BA[f] = wfr[f * 64 + lane];   // tap 0

  __syncthreads();   // drains global_load_lds (vmcnt) + orders halo for all waves

  const int r15 = lane & 15;
  const int hi4 = lane >> 4;

  auto loadB = [&](s16x8* dst, int tap) {
    #pragma unroll
    for (int f = 0; f < 8; ++f) dst[f] = wfr[(tap * 8 + f) * 64 + lane];
  };

  auto compute = [&](int tap, const s16x8* B) {
    int kd = tap / 9;
    int rem9 = tap - kd * 9;
    int kh = rem9 / 3;
    int kw = rem9 - kh * 3;
    #pragma unroll
    for (int st2 = 0; st2 < 2; ++st2) {
      s16x8 a[4];
      #pragma unroll
      for (int mf = 0; mf < 4; ++mf) {
        int dy   = mf >> 1;
        int plane = (w + kd) * 4 + (dy + kh);
        int hx   = (mf & 1) * 16 + r15 + kw;
        int slot = (st2 * 4 + hi4) ^ (hx & 7);
        a[mf] = *(const s16x8*)&halo[(plane * 34 + hx) * 128 + slot * 16];
      }
      #pragma unroll
      for (int mf = 0; mf < 4; ++mf)
        #pragma unroll
        for (int nf = 0; nf < 4; ++nf)
          acc[mf][nf] = __builtin_amdgcn_mfma_f32_16x16x32_bf16(
              a[mf], B[st2 * 4 + nf], acc[mf][nf], 0, 0, 0);
    }
  };

  // 27 taps, B double-buffered in registers, static indexing throughout
  for (int t = 0; t < 13; ++t) {
    loadB(BB, 2 * t + 1);
    compute(2 * t, BA);
    loadB(BA, 2 * t + 2);
    compute(2 * t + 1, BB);
  }
  compute(26, BA);

  // ---- epilogue: D row = spatial x (within 16-frag), col = cout ----
  const int z = z0 + w;
  #pragma unroll
  for (int nf = 0; nf < 4; ++nf) {
    int cout = nf * 16 + r15;
    float bv = bias[cout];
    #pragma unroll
    for (int mf = 0; mf < 4; ++mf) {
      int y  = y0 + (mf >> 1);
      int x0 = (mf & 1) * 16 + 4 * hi4;
      float* orow = out + ((size_t)((b * 64 + cout) * 32 + z) * 32 + y) * 32;
      f32x4 v;
      #pragma unroll
      for (int r = 0; r < 4; ++r) v[r] = acc[mf][nf][r] + bv;
      *(f32x4*)&orow[x0] = v;
    }
  }
}

extern "C" void kernel_launch(void* const* d_in, const int* in_sizes, int n_in,
                              void* d_out, int out_size, void* d_ws, size_t ws_size,
                              hipStream_t stream) {
  const float* x    = (const float*)d_in[0];
  const float* wgt  = (const float*)d_in[1];
  const float* bias = (const float*)d_in[2];
  float* out = (float*)d_out;
  char* ws = (char*)d_ws;

  prep_kernel<<<4528, 256, 0, stream>>>(x, wgt,
                                        (unsigned short*)(ws + WS_W_OFF),
                                        (float*)(ws + WS_ZERO_OFF),
                                        (unsigned short*)(ws + WS_XT_OFF));
  conv_kernel<<<1024, 128, 0, stream>>>(bias, out, ws);
}

// Round 3
// 54.656 us; speedup vs baseline: 1.1703x; 1.1703x over previous
//
#include <hip/hip_runtime.h>
#include <hip/hip_bf16.h>

// ws layout (requires ws_size >= 17039360 B):
//   [0, 221184)        : weights as bf16 in MFMA B-fragment order
//   [221184, 221440)   : 256 B of zeros (OOB halo source)
//   [262144, 17039360) : x_t = x transposed to [b][s][c] bf16 (16 MiB)
#define WS_W_OFF    0
#define WS_ZERO_OFF 221184
#define WS_XT_OFF   262144

typedef __attribute__((ext_vector_type(8))) short s16x8;
typedef __attribute__((ext_vector_type(4))) float f32x4;

#define GLOBAL_AS __attribute__((address_space(1)))
#define LDS_AS    __attribute__((address_space(3)))

__device__ __forceinline__ unsigned short f2bf(float f) {
  // round-to-nearest-even bf16 (inputs are normal randoms; no NaN handling needed)
  unsigned u = __builtin_bit_cast(unsigned, f);
  u = u + 0x7fffu + ((u >> 16) & 1u);
  return (unsigned short)(u >> 16);
}

// ---------------------------------------------------------------------------
// Fused prep: blocks [0,432) repack weights; blocks [432,4528) transpose x.
//
// Weights: W[cout][cin][tap] fp32 -> bf16 fragments.
// Fragment f = (tap*2+st2)*4+nf holds B[n][k] for n = nf*16 + (lane&15),
// cin = st2*32 + (lane>>4)*8 + j  (16x16x32 MFMA B layout, contiguous-k per lane).
// bf16 index = (f*64 + lane)*8 + j.
//
// x: NCDHW fp32 -> x_t[b][s][c] bf16 (channels-last). Reads coalesced along s.
__global__ void prep_kernel(const float* __restrict__ x,
                            const float* __restrict__ w,
                            unsigned short* __restrict__ wsw,
                            float* __restrict__ zeros,
                            unsigned short* __restrict__ xt) {
  int blk = blockIdx.x;
  if (blk < 432) {
    int t = blk * 256 + threadIdx.x;             // 110592 threads exactly
    int tap  = t % 27;
    int cin  = (t / 27) & 63;
    int cout = t / (27 * 64);
    int st2 = cin >> 5;
    int q   = (cin >> 3) & 3;
    int j   = cin & 7;
    int nf  = cout >> 4;
    int lane = q * 16 + (cout & 15);
    int dst = (((tap * 2 + st2) * 4 + nf) * 64 + lane) * 8 + j;
    wsw[dst] = f2bf(w[t]);
    if (t < 64) zeros[t] = 0.0f;
  } else {
    int t  = (blk - 432) * 256 + threadIdx.x;    // 1048576 threads
    int s  = t & 32767;
    int c8 = (t >> 15) & 7;
    int b  = t >> 18;
    const float* src = x + (size_t)(b * 64 + c8 * 8) * 32768 + s;
    s16x8 v;
    #pragma unroll
    for (int k = 0; k < 8; ++k) v[k] = (short)f2bf(src[(size_t)k * 32768]);
    *(s16x8*)(xt + (size_t)(b * 32768 + s) * 64 + c8 * 8) = v;
  }
}

// ---------------------------------------------------------------------------
// Implicit-GEMM conv, cin-split for occupancy.
// Block = (b, z, y-quad): 1z x 4y x 32x = 128 outputs x 64 couts. 4 waves,
// wave w owns y-row y0+w (M_w = 32). K = 64 processed as two cin-halves of 32;
// halo staged per half: 3z x 6y x 34x positions x 32cin x 2B = 39168 B ->
// 4 blocks/CU -> 16 waves/CU = 4 waves/SIMD (TLP hides ds_read/B-load latency).
// Per half: 27 taps, zero barriers; B double-buffered in regs from L2-resident ws.
//
// Halo layout: granule g (1 KiB) = positions [g*16, g*16+16), chunk index
// c(pos, slot) = (pos&15)*4 + (slot ^ ((pos>>2)&3))  (slot = 16B cin-chunk).
// This puts exactly 2 lanes per bank-group on the A ds_read_b128 (2-way = free).
// Staged linearly (lane L -> byte g*1024 + L*16) with inverse-swizzled SOURCE:
// lane L reads source (pos = g*16 + (L>>2), slot = (L&3) ^ ((L>>4)&3)).
__global__ __launch_bounds__(256, 4) void conv_kernel(const float* __restrict__ bias,
                                                      float* __restrict__ out,
                                                      const char* __restrict__ ws) {
  __shared__ unsigned char halo[39 * 1024];      // 39936 B (612 pos + pad)

  const int tid  = threadIdx.x;
  const int lane = tid & 63;
  const int w    = tid >> 6;                     // wave id 0..3 = local y-row
  // XCD-aware swizzle (1024 % 8 == 0 -> simple form bijective): each XCD gets a
  // contiguous 128-tile chunk -> its halo slab (~2.3 MB) fits the 4 MB L2.
  const int logical = (blockIdx.x & 7) * 128 + (blockIdx.x >> 3);
  const int yt = logical & 7, z = (logical >> 3) & 31, b = logical >> 8;
  const int y0 = yt * 4;

  const int r15 = lane & 15;
  const int hi4 = lane >> 4;

  // staging constants
  const int sl_sub  = lane >> 2;                           // pos within granule
  const int sl_slot = (lane & 3) ^ ((lane >> 4) & 3);      // source cin-chunk

  auto stage = [&](int h) {
    for (int g = w; g < 39; g += 4) {
      int pos = g * 16 + sl_sub;
      int hz = pos / 204; int rem = pos - hz * 204;        // 204 = 6*34
      int hy = rem / 34;  int hx = rem - hy * 34;
      int gz = z + hz - 1, gy = y0 + hy - 1, gx = hx - 1;
      bool inb = (pos < 612) & ((unsigned)gz < 32u) &
                 ((unsigned)gy < 32u) & ((unsigned)gx < 32u);
      int s = (gz * 32 + gy) * 32 + gx;
      int src = inb ? (WS_XT_OFF + (b * 32768 + s) * 128 + h * 64 + sl_slot * 16)
                    : WS_ZERO_OFF;
      __builtin_amdgcn_global_load_lds(
          (const GLOBAL_AS void*)(ws + src),
          (LDS_AS void*)(&halo[g * 1024 + lane * 16]),
          16, 0, 0);
    }
  };

  const s16x8* __restrict__ wfr = (const s16x8*)(ws + WS_W_OFF);

  f32x4 zero4 = {0.f, 0.f, 0.f, 0.f};
  f32x4 acc[2][4];
  #pragma unroll
  for (int mf = 0; mf < 2; ++mf)
    #pragma unroll
    for (int nf = 0; nf < 4; ++nf) acc[mf][nf] = zero4;

  s16x8 BA[4], BB[4];

  auto loadB = [&](s16x8* dst, int h, int tap) {
    #pragma unroll
    for (int nf = 0; nf < 4; ++nf)
      dst[nf] = wfr[((tap * 2 + h) * 4 + nf) * 64 + lane];
  };

  auto compute = [&](int tap, const s16x8* B) {
    int kd = tap / 9; int rem9 = tap - kd * 9;
    int kh = rem9 / 3; int kw = rem9 - kh * 3;
    int prow = (kd * 6 + w + kh) * 34 + r15 + kw;          // halo position, mf=0
    s16x8 a[2];
    #pragma unroll
    for (int mf = 0; mf < 2; ++mf) {
      int pos  = prow + mf * 16;
      int addr = ((pos >> 4) << 10) | ((pos & 15) << 6)
               | ((hi4 ^ ((pos >> 2) & 3)) << 4);
      a[mf] = *(const s16x8*)&halo[addr];
    }
    #pragma unroll
    for (int mf = 0; mf < 2; ++mf)
      #pragma unroll
      for (int nf = 0; nf < 4; ++nf)
        acc[mf][nf] = __builtin_amdgcn_mfma_f32_16x16x32_bf16(
            a[mf], B[nf], acc[mf][nf], 0, 0, 0);
  };

  // ---- half 0 ----
  stage(0);
  loadB(BA, 0, 0);                 // overlaps with staging
  __syncthreads();                 // drains global_load_lds + orders halo
  for (int t = 0; t < 13; ++t) {
    loadB(BB, 0, 2 * t + 1); compute(2 * t, BA);
    loadB(BA, 0, 2 * t + 2); compute(2 * t + 1, BB);
  }
  compute(26, BA);

  // ---- half 1 ----
  loadB(BA, 1, 0);                 // prefetch before the barrier
  __syncthreads();                 // all waves done reading half-0 halo
  stage(1);
  __syncthreads();                 // half-1 halo ready
  for (int t = 0; t < 13; ++t) {
    loadB(BB, 1, 2 * t + 1); compute(2 * t, BA);
    loadB(BA, 1, 2 * t + 2); compute(2 * t + 1, BB);
  }
  compute(26, BA);

  // ---- epilogue: D row = x (within 16-frag), col = cout ----
  const int y = y0 + w;
  #pragma unroll
  for (int nf = 0; nf < 4; ++nf) {
    int cout = nf * 16 + r15;
    float bv = bias[cout];
    float* orow = out + ((size_t)((b * 64 + cout) * 32 + z) * 32 + y) * 32;
    #pragma unroll
    for (int mf = 0; mf < 2; ++mf) {
      int x0 = mf * 16 + 4 * hi4;
      f32x4 v;
      #pragma unroll
      for (int r = 0; r < 4; ++r) v[r] = acc[mf][nf][r] + bv;
      *(f32x4*)&orow[x0] = v;
    }
  }
}

extern "C" void kernel_launch(void* const* d_in, const int* in_sizes, int n_in,
                              void* d_out, int out_size, void* d_ws, size_t ws_size,
                              hipStream_t stream) {
  const float* x    = (const float*)d_in[0];
  const float* wgt  = (const float*)d_in[1];
  const float* bias = (const float*)d_in[2];
  float* out = (float*)d_out;
  char* ws = (char*)d_ws;

  prep_kernel<<<4528, 256, 0, stream>>>(x, wgt,
                                        (unsigned short*)(ws + WS_W_OFF),
                                        (float*)(ws + WS_ZERO_OFF),
                                        (unsigned short*)(ws + WS_XT_OFF));
  conv_kernel<<<1024, 256, 0, stream>>>(bias, out, ws);
}

// Round 4
// 49.069 us; speedup vs baseline: 1.3036x; 1.1139x over previous
//
#include <hip/hip_runtime.h>
#include <hip/hip_bf16.h>

// ws layout (requires ws_size >= 17039360 B):
//   [0, 221184)        : weights as bf16 in MFMA B-fragment order
//   [221184, 221440)   : 256 B of zeros (OOB halo source)
//   [262144, 17039360) : x_t = x transposed to [b][s][c] bf16 (16 MiB)
#define WS_W_OFF    0
#define WS_ZERO_OFF 221184
#define WS_XT_OFF   262144

typedef __attribute__((ext_vector_type(8))) short s16x8;
typedef __attribute__((ext_vector_type(4))) float f32x4;

#define GLOBAL_AS __attribute__((address_space(1)))
#define LDS_AS    __attribute__((address_space(3)))

__device__ __forceinline__ unsigned short f2bf(float f) {
  // round-to-nearest-even bf16 (inputs are normal randoms; no NaN handling needed)
  unsigned u = __builtin_bit_cast(unsigned, f);
  u = u + 0x7fffu + ((u >> 16) & 1u);
  return (unsigned short)(u >> 16);
}

// ---------------------------------------------------------------------------
// Fused prep: blocks [0,432) repack weights; blocks [432,4528) transpose x.
//
// Weights: W[cout][cin][tap] fp32 -> bf16 fragments.
// Fragment f = (tap*2+h)*4+nf holds B[n][k] for n = nf*16 + (lane&15),
// cin = h*32 + (lane>>4)*8 + j  (16x16x32 MFMA B layout, contiguous-k per lane).
// bf16 index = (f*64 + lane)*8 + j.
//
// x: NCDHW fp32 -> x_t[b][s][c] bf16 (channels-last). Reads coalesced along s.
__global__ void prep_kernel(const float* __restrict__ x,
                            const float* __restrict__ w,
                            unsigned short* __restrict__ wsw,
                            float* __restrict__ zeros,
                            unsigned short* __restrict__ xt) {
  int blk = blockIdx.x;
  if (blk < 432) {
    int t = blk * 256 + threadIdx.x;             // 110592 threads exactly
    int tap  = t % 27;
    int cin  = (t / 27) & 63;
    int cout = t / (27 * 64);
    int h   = cin >> 5;
    int q   = (cin >> 3) & 3;
    int j   = cin & 7;
    int nf  = cout >> 4;
    int lane = q * 16 + (cout & 15);
    int dst = (((tap * 2 + h) * 4 + nf) * 64 + lane) * 8 + j;
    wsw[dst] = f2bf(w[t]);
    if (t < 64) zeros[t] = 0.0f;
  } else {
    int t  = (blk - 432) * 256 + threadIdx.x;    // 1048576 threads
    int s  = t & 32767;
    int c8 = (t >> 15) & 7;
    int b  = t >> 18;
    const float* src = x + (size_t)(b * 64 + c8 * 8) * 32768 + s;
    s16x8 v;
    #pragma unroll
    for (int k = 0; k < 8; ++k) v[k] = (short)f2bf(src[(size_t)k * 32768]);
    *(s16x8*)(xt + (size_t)(b * 32768 + s) * 64 + c8 * 8) = v;
  }
}

// ---------------------------------------------------------------------------
// Implicit-GEMM conv, M_w = 64 to halve B-operand cache traffic.
// Block = (b, z, y-quad): 1z x 4y x 32x = 128 outputs x 64 couts, 128 threads
// = 2 waves. Wave w owns y-rows {y0+2w, y0+2w+1}: M_w = 64, so B-bytes/FLOP
// = 1/64 -> 1.77 MB/CU L1 traffic (~28K cy) < MFMA wall (33.5K cy).
// K = 64 as two cin-halves of 32; halo per half: 3z x 6y x 34x pos x 64 B
// = 39168 B -> 4 blocks/CU -> 8 waves/CU = 2 waves/SIMD (all the waves the
// problem provides at this tiling). A and B double-buffered one tap ahead.
//
// Halo layout is LINEAR: position pos at halo[pos*64], cin-chunk c (16 B) at
// +c*16. A-read (lane l: pos+= l&15, chunk = l>>4) hits bank-group
// (4*(l&15) + (l>>4)) & 7 -> exactly 8 lanes per group: conflict-free, no
// swizzle needed (round-3's swizzle showed 1.47M conflict cycles).
__global__ __launch_bounds__(128, 2) void conv_kernel(const float* __restrict__ bias,
                                                      float* __restrict__ out,
                                                      const char* __restrict__ ws) {
  __shared__ unsigned char halo[39 * 1024];      // 624 positions (612 used)

  const int tid  = threadIdx.x;
  const int lane = tid & 63;
  const int w    = tid >> 6;                     // wave id 0..1 = y-pair
  // XCD-aware swizzle (1024 % 8 == 0 -> bijective): each XCD gets a contiguous
  // 128-block chunk (fixed b, 16 consecutive z) -> ~2.3 MB x_t slab fits L2.
  const int logical = (blockIdx.x & 7) * 128 + (blockIdx.x >> 3);
  const int yt = logical & 7, z = (logical >> 3) & 31, b = logical >> 8;
  const int y0 = yt * 4;

  const int r15 = lane & 15;
  const int hi4 = lane >> 4;

  // staging: granule = 1024 B = 16 positions; lane l -> pos g*16 + (l>>2),
  // 16B chunk l&3. All linear (dest and source), conflict-free.
  const int sl_sub   = lane >> 2;
  const int sl_chunk = lane & 3;

  auto stage = [&](int h) {
    for (int g = w; g < 39; g += 2) {
      int pos = g * 16 + sl_sub;
      int hz = pos / 204; int rem = pos - hz * 204;        // 204 = 6*34
      int hy = rem / 34;  int hx = rem - hy * 34;
      int gz = z + hz - 1, gy = y0 + hy - 1, gx = hx - 1;
      bool inb = (pos < 612) & ((unsigned)gz < 32u) &
                 ((unsigned)gy < 32u) & ((unsigned)gx < 32u);
      int s = (gz * 32 + gy) * 32 + gx;
      int src = inb ? (WS_XT_OFF + (b * 32768 + s) * 128 + h * 64 + sl_chunk * 16)
                    : WS_ZERO_OFF;
      __builtin_amdgcn_global_load_lds(
          (const GLOBAL_AS void*)(ws + src),
          (LDS_AS void*)(&halo[g * 1024 + lane * 16]),
          16, 0, 0);
    }
  };

  const s16x8* __restrict__ wfr = (const s16x8*)(ws + WS_W_OFF);

  f32x4 zero4 = {0.f, 0.f, 0.f, 0.f};
  f32x4 acc[4][4];
  #pragma unroll
  for (int mf = 0; mf < 4; ++mf)
    #pragma unroll
    for (int nf = 0; nf < 4; ++nf) acc[mf][nf] = zero4;

  s16x8 B0[4], B1[4], A0[4], A1[4];

  auto loadB = [&](s16x8* dst, int h, int tap) {
    #pragma unroll
    for (int nf = 0; nf < 4; ++nf)
      dst[nf] = wfr[((tap * 2 + h) * 4 + nf) * 64 + lane];
  };

  // A fragment for tap: mf = (dy = mf>>1, xh = mf&1); lane l reads position
  // prow + dy*34 + xh*16 + (l&15), cin-chunk l>>4 (k = (l>>4)*8+j).
  auto loadA = [&](s16x8* a, int tap) {
    int kd = tap / 9; int r9 = tap - kd * 9;
    int kh = r9 / 3;  int kw = r9 - kh * 3;
    int prow = (kd * 6 + 2 * w + kh) * 34 + kw + r15;
    #pragma unroll
    for (int mf = 0; mf < 4; ++mf) {
      int pos = prow + (mf >> 1) * 34 + (mf & 1) * 16;
      a[mf] = *(const s16x8*)&halo[pos * 64 + hi4 * 16];
    }
  };

  auto compute = [&](const s16x8* a, const s16x8* B) {
    #pragma unroll
    for (int mf = 0; mf < 4; ++mf)
      #pragma unroll
      for (int nf = 0; nf < 4; ++nf)
        acc[mf][nf] = __builtin_amdgcn_mfma_f32_16x16x32_bf16(
            a[mf], B[nf], acc[mf][nf], 0, 0, 0);
  };

  #pragma unroll 1
  for (int h = 0; h < 2; ++h) {
    if (h) __syncthreads();          // all waves done reading half-0 halo
    stage(h);                        // issue async loads (latency overlaps loadB)
    loadB(B0, h, 0);
    __syncthreads();                 // drains vmcnt + orders halo for all waves
    loadA(A0, 0);
    for (int t = 0; t < 13; ++t) {
      loadB(B1, h, 2 * t + 1); loadA(A1, 2 * t + 1); compute(A0, B0);
      loadB(B0, h, 2 * t + 2); loadA(A0, 2 * t + 2); compute(A1, B1);
    }
    compute(A0, B0);                 // tap 26
  }

  // ---- epilogue: D row = x (within 16-frag), col = cout (round-1 verified) ----
  #pragma unroll
  for (int nf = 0; nf < 4; ++nf) {
    int cout = nf * 16 + r15;
    float bv = bias[cout];
    #pragma unroll
    for (int mf = 0; mf < 4; ++mf) {
      int y  = y0 + 2 * w + (mf >> 1);
      int x0 = (mf & 1) * 16 + 4 * hi4;
      float* orow = out + ((size_t)((b * 64 + cout) * 32 + z) * 32 + y) * 32;
      f32x4 v;
      #pragma unroll
      for (int r = 0; r < 4; ++r) v[r] = acc[mf][nf][r] + bv;
      *(f32x4*)&orow[x0] = v;
    }
  }
}

extern "C" void kernel_launch(void* const* d_in, const int* in_sizes, int n_in,
                              void* d_out, int out_size, void* d_ws, size_t ws_size,
                              hipStream_t stream) {
  const float* x    = (const float*)d_in[0];
  const float* wgt  = (const float*)d_in[1];
  const float* bias = (const float*)d_in[2];
  float* out = (float*)d_out;
  char* ws = (char*)d_ws;

  prep_kernel<<<4528, 256, 0, stream>>>(x, wgt,
                                        (unsigned short*)(ws + WS_W_OFF),
                                        (float*)(ws + WS_ZERO_OFF),
                                        (unsigned short*)(ws + WS_XT_OFF));
  conv_kernel<<<1024, 128, 0, stream>>>(bias, out, ws);
}

// Round 5
// 46.203 us; speedup vs baseline: 1.3844x; 1.0620x over previous
//
#include <hip/hip_runtime.h>
#include <hip/hip_bf16.h>

// ws layout (requires ws_size >= 17039360 B):
//   [0, 221184)        : weights as bf16 in MFMA B-fragment order
//   [221184, 221440)   : 256 B of zeros (OOB halo source)
//   [262144, 17039360) : x_t = x transposed to [b][s][c] bf16 (16 MiB)
#define WS_W_OFF    0
#define WS_ZERO_OFF 221184
#define WS_XT_OFF   262144

typedef __attribute__((ext_vector_type(8))) short s16x8;
typedef __attribute__((ext_vector_type(4))) float f32x4;

#define GLOBAL_AS __attribute__((address_space(1)))
#define LDS_AS    __attribute__((address_space(3)))

__device__ __forceinline__ unsigned short f2bf(float f) {
  // round-to-nearest-even bf16 (inputs are normal randoms; no NaN handling needed)
  unsigned u = __builtin_bit_cast(unsigned, f);
  u = u + 0x7fffu + ((u >> 16) & 1u);
  return (unsigned short)(u >> 16);
}

// ---------------------------------------------------------------------------
// Fused prep: blocks [0,432) repack weights; blocks [432,4528) transpose x.
//
// Weights: W[cout][cin][tap] fp32 -> bf16 fragments.
// Fragment f = (tap*2+h)*4+nf holds B[n][k] for n = nf*16 + (lane&15),
// cin = h*32 + (lane>>4)*8 + j  (16x16x32 MFMA B layout, contiguous-k per lane).
// bf16 index = (f*64 + lane)*8 + j.
//
// x: NCDHW fp32 -> x_t[b][s][c] bf16 (channels-last). Reads coalesced along s.
__global__ void prep_kernel(const float* __restrict__ x,
                            const float* __restrict__ w,
                            unsigned short* __restrict__ wsw,
                            float* __restrict__ zeros,
                            unsigned short* __restrict__ xt) {
  int blk = blockIdx.x;
  if (blk < 432) {
    int t = blk * 256 + threadIdx.x;             // 110592 threads exactly
    int tap  = t % 27;
    int cin  = (t / 27) & 63;
    int cout = t / (27 * 64);
    int h   = cin >> 5;
    int q   = (cin >> 3) & 3;
    int j   = cin & 7;
    int nf  = cout >> 4;
    int lane = q * 16 + (cout & 15);
    int dst = (((tap * 2 + h) * 4 + nf) * 64 + lane) * 8 + j;
    wsw[dst] = f2bf(w[t]);
    if (t < 64) zeros[t] = 0.0f;
  } else {
    int t  = (blk - 432) * 256 + threadIdx.x;    // 1048576 threads
    int s  = t & 32767;
    int c8 = (t >> 15) & 7;
    int b  = t >> 18;
    const float* src = x + (size_t)(b * 64 + c8 * 8) * 32768 + s;
    s16x8 v;
    #pragma unroll
    for (int k = 0; k < 8; ++k) v[k] = (short)f2bf(src[(size_t)k * 32768]);
    *(s16x8*)(xt + (size_t)(b * 32768 + s) * 64 + c8 * 8) = v;
  }
}

// ---------------------------------------------------------------------------
// Implicit-GEMM conv. Block = (b, z-pair, y-quad): 2z x 4y x 32x = 256 outputs
// x 64 couts, 256 threads = 4 waves. Wave w owns z = z0+(w>>1), y-rows
// {y0+2(w&1), +1}: M_w = 64. The 4 barrier-synced waves stream the SAME B tap
// sequence in near-lockstep -> 3/4 L1 hits; per-CU L2 B-traffic ~0.43 MB.
// K = 64 as two cin-halves of 32; halo per half: 4z x 6y x 34x pos x 64 B =
// 52224 B LDS -> grid 512 = 2 blocks/CU = 8 waves/CU (2/SIMD).
// A and B triple-buffered (depth-2 prefetch ~310 cy wave-time > L2 latency).
//
// Halo layout LINEAR: position pos at halo[pos*64], cin-chunk c (16 B) at
// +c*16. A-read (lane l: pos += l&15, chunk = l>>4): each bank gets exactly
// 8 of the wave's 256 dwords -> at the 8-cycle b128 floor, conflict-free.
__global__ __launch_bounds__(256, 2) void conv_kernel(const float* __restrict__ bias,
                                                      float* __restrict__ out,
                                                      const char* __restrict__ ws) {
  __shared__ unsigned char halo[52 * 1024];      // 832 positions (816 used)

  const int tid  = threadIdx.x;
  const int lane = tid & 63;
  const int w    = tid >> 6;                     // wave id 0..3
  // XCD-aware swizzle (512 % 8 == 0 -> bijective): each XCD gets 64 contiguous
  // logical blocks (fixed b, 8 consecutive z-pairs) -> ~2.4 MB x_t slab in L2.
  const int logical = (blockIdx.x & 7) * 64 + (blockIdx.x >> 3);
  const int yt = logical & 7, zt = (logical >> 3) & 15, b = logical >> 7;
  const int z0 = zt * 2, y0 = yt * 4;
  const int zo  = w >> 1;                        // wave z within pair
  const int yo2 = (w & 1) * 2;                   // wave y-pair base

  const int r15 = lane & 15;
  const int hi4 = lane >> 4;

  // staging: granule = 1024 B = 16 positions; lane l -> pos g*16 + (l>>2),
  // 16B chunk l&3. All linear (dest and source).
  const int sl_sub   = lane >> 2;
  const int sl_chunk = lane & 3;

  auto stage = [&](int h) {
    for (int g = w; g < 52; g += 4) {            // 13 granules per wave
      int pos = g * 16 + sl_sub;
      int hz = pos / 204; int rem = pos - hz * 204;        // 204 = 6*34
      int hy = rem / 34;  int hx = rem - hy * 34;
      int gz = z0 + hz - 1, gy = y0 + hy - 1, gx = hx - 1;
      bool inb = (pos < 816) & ((unsigned)gz < 32u) &
                 ((unsigned)gy < 32u) & ((unsigned)gx < 32u);
      int s = (gz * 32 + gy) * 32 + gx;
      int src = inb ? (WS_XT_OFF + (b * 32768 + s) * 128 + h * 64 + sl_chunk * 16)
                    : WS_ZERO_OFF;
      __builtin_amdgcn_global_load_lds(
          (const GLOBAL_AS void*)(ws + src),
          (LDS_AS void*)(&halo[g * 1024 + lane * 16]),
          16, 0, 0);
    }
  };

  const s16x8* __restrict__ wfr = (const s16x8*)(ws + WS_W_OFF);

  f32x4 zero4 = {0.f, 0.f, 0.f, 0.f};
  f32x4 acc[4][4];
  #pragma unroll
  for (int mf = 0; mf < 4; ++mf)
    #pragma unroll
    for (int nf = 0; nf < 4; ++nf) acc[mf][nf] = zero4;

  s16x8 B0[4], B1[4], B2[4], A0[4], A1[4], A2[4];

  auto loadB = [&](s16x8* dst, int h, int tap) {
    #pragma unroll
    for (int nf = 0; nf < 4; ++nf)
      dst[nf] = wfr[((tap * 2 + h) * 4 + nf) * 64 + lane];
  };

  // A fragment for tap: mf = (dy = mf>>1, xh = mf&1); lane l reads position
  // base + dy*34 + xh*16 + (l&15), cin-chunk l>>4 (k = (l>>4)*8 + j).
  auto loadA = [&](s16x8* a, int tap) {
    int kd = tap / 9; int r9 = tap - kd * 9;
    int kh = r9 / 3;  int kw = r9 - kh * 3;
    int base = ((zo + kd) * 6 + (yo2 + kh)) * 34 + kw + r15;
    #pragma unroll
    for (int mf = 0; mf < 4; ++mf) {
      int pos = base + (mf >> 1) * 34 + (mf & 1) * 16;
      a[mf] = *(const s16x8*)&halo[pos * 64 + hi4 * 16];
    }
  };

  auto compute = [&](const s16x8* a, const s16x8* B) {
    #pragma unroll
    for (int mf = 0; mf < 4; ++mf)
      #pragma unroll
      for (int nf = 0; nf < 4; ++nf)
        acc[mf][nf] = __builtin_amdgcn_mfma_f32_16x16x32_bf16(
            a[mf], B[nf], acc[mf][nf], 0, 0, 0);
  };

  // 27 taps per half, A/B triple-buffered 2 taps ahead, static indexing.
  auto khalf = [&](int h) {
    loadA(A0, 0);
    #pragma unroll 1
    for (int t = 0; t < 8; ++t) {                // taps 3t .. 3t+2
      loadB(B2, h, 3 * t + 2); loadA(A1, 3 * t + 1); compute(A0, B0);
      loadB(B0, h, 3 * t + 3); loadA(A2, 3 * t + 2); compute(A1, B1);
      loadB(B1, h, 3 * t + 4); loadA(A0, 3 * t + 3); compute(A2, B2);
    }
    loadB(B2, h, 26); loadA(A1, 25); compute(A0, B0);   // tap 24
    loadA(A2, 26);    compute(A1, B1);                  // tap 25
    compute(A2, B2);                                    // tap 26
  };

  stage(0);
  loadB(B0, 0, 0); loadB(B1, 0, 1);  // overlaps staging latency
  __syncthreads();                   // drains vmcnt + orders halo for all waves
  khalf(0);

  loadB(B0, 1, 0); loadB(B1, 1, 1);  // prefetch half-1 B (doesn't touch halo)
  __syncthreads();                   // all waves done reading half-0 halo
  stage(1);
  __syncthreads();                   // half-1 halo ready
  khalf(1);

  // ---- epilogue: D row = x (within 16-frag), col = cout (round-1 verified) ----
  const int z = z0 + zo;
  #pragma unroll
  for (int nf = 0; nf < 4; ++nf) {
    int cout = nf * 16 + r15;
    float bv = bias[cout];
    #pragma unroll
    for (int mf = 0; mf < 4; ++mf) {
      int y  = y0 + yo2 + (mf >> 1);
      int x0 = (mf & 1) * 16 + 4 * hi4;
      float* orow = out + ((size_t)((b * 64 + cout) * 32 + z) * 32 + y) * 32;
      f32x4 v;
      #pragma unroll
      for (int r = 0; r < 4; ++r) v[r] = acc[mf][nf][r] + bv;
      *(f32x4*)&orow[x0] = v;
    }
  }
}

extern "C" void kernel_launch(void* const* d_in, const int* in_sizes, int n_in,
                              void* d_out, int out_size, void* d_ws, size_t ws_size,
                              hipStream_t stream) {
  const float* x    = (const float*)d_in[0];
  const float* wgt  = (const float*)d_in[1];
  const float* bias = (const float*)d_in[2];
  float* out = (float*)d_out;
  char* ws = (char*)d_ws;

  prep_kernel<<<4528, 256, 0, stream>>>(x, wgt,
                                        (unsigned short*)(ws + WS_W_OFF),
                                        (float*)(ws + WS_ZERO_OFF),
                                        (unsigned short*)(ws + WS_XT_OFF));
  conv_kernel<<<512, 256, 0, stream>>>(bias, out, ws);
}